// Round 5
// baseline (128.568 us; speedup 1.0000x reference)
//
#include <hip/hip_runtime.h>
#include <hip/hip_bf16.h>

#define B 4096
#define S 200
#define EMB_DIM 128
#define HIDDEN 256
#define NUM_CLASSES 20
#define VOCAB 100000
#define RB 8               // batch rows per block = waves per block
#define NT (RB * 64)       // 512 threads
#define SP 208             // max padded positions (ceil(200/16)*16)

typedef __attribute__((ext_vector_type(8))) unsigned short ushort8;

// RNE float -> bf16 (inputs finite)
__device__ __forceinline__ unsigned short f2bf(float f) {
    unsigned u = __float_as_uint(f);
    unsigned r = u + 0x7fffu + ((u >> 16) & 1u);
    return (unsigned short)(r >> 16);
}

// ---------------------------------------------------------------------------
// Pass 1: stream-convert fp32 table (51.2 MB, cold: the harness's 268 MB ws
// re-poison flushes L3 every iteration) -> 25.6 MB bf16 table in d_ws.
// Sequential HBM at ~6 TB/s; leaves the bf16 table L3-resident for pass 2.
// ---------------------------------------------------------------------------
__global__ __launch_bounds__(256) void convert_kernel(
    const float* __restrict__ emb,
    unsigned short* __restrict__ embh)
{
    const long i = ((long)blockIdx.x * 256 + threadIdx.x) * 8;
    const float4 a = *(const float4*)(emb + i);
    const float4 b = *(const float4*)(emb + i + 4);
    ushort8 o;
    o[0] = f2bf(a.x); o[1] = f2bf(a.y); o[2] = f2bf(a.z); o[3] = f2bf(a.w);
    o[4] = f2bf(b.x); o[5] = f2bf(b.y); o[6] = f2bf(b.z); o[7] = f2bf(b.w);
    *(ushort8*)(embh + i) = o;
}

// ---------------------------------------------------------------------------
// Pass 2: fused gather + mean-pool + MLP. One WAVE per batch row.
// 512 blocks x 512 threads (8 waves); wave w owns row blockIdx*8 + w.
//
// Gather: wave = 4 position-groups x 16 lanes; lane slot d=lane&15 loads
// bytes [16d,16d+16) of the 256B bf16 row. 4-deep unroll -> 16 positions
// per round, rows padded to 16 (vs 64 in round 4), indices prefetched from
// LDS before the vmcnt wait. Positions >= L gather row 0 (zeros).
// Cross-group reduce via __shfl_down(32/16) -- no LDS tmp, no per-row
// barriers, waves fully independent until the single pre-MLP barrier.
//
// MLP: thread t computes hidden unit t&255 for 4 rows (both half-blocks
// read the same W1 addresses -> W1 fetched once per block = 67 MB total
// L2 traffic vs 268 MB in round 4).
// ---------------------------------------------------------------------------
__global__ __launch_bounds__(NT) void fused_kernel(
    const int* __restrict__ x,               // [B, S]
    const int* __restrict__ lens,            // [B]
    const unsigned short* __restrict__ embh, // [VOCAB, EMB_DIM] bf16
    const float* __restrict__ W1,            // [EMB_DIM, HIDDEN]
    const float* __restrict__ b1,            // [HIDDEN]
    const float* __restrict__ W2,            // [HIDDEN, NUM_CLASSES]
    const float* __restrict__ b2,            // [NUM_CLASSES]
    float* __restrict__ out)                 // [B, NUM_CLASSES]
{
    __shared__ int   sidx[RB][SP];       // 6.5 KB
    __shared__ float P[RB][EMB_DIM];     // 4 KB
    __shared__ float H[RB][HIDDEN];      // 8 KB

    const int t    = threadIdx.x;
    const int w    = t >> 6;             // wave / row-in-block
    const int lane = t & 63;
    const int b0   = blockIdx.x * RB;
    const int row  = b0 + w;
    const int L    = lens[row];

    // Stage this wave's indices; positions >= L map to row 0 (zeros).
    for (int p = lane; p < SP; p += 64) {
        int v = 0;
        if (p < L) v = x[(long)row * S + p];
        sidx[w][p] = v;
    }
    __syncthreads();

    const int g = lane >> 4;             // position group 0..3
    const int d = lane & 15;             // 16B slot within 256B row

    const int nR = (L + 15) >> 4;        // rounds of 16 positions (1..13)

    float acc[4][8];
    #pragma unroll
    for (int j = 0; j < 4; ++j)
        #pragma unroll
        for (int f = 0; f < 8; ++f) acc[j][f] = 0.f;

    int cur[4], nxt[4];
    #pragma unroll
    for (int j = 0; j < 4; ++j) cur[j] = sidx[w][g + 4 * j];

    for (int it = 0; it < nR; ++it) {
        uint4 v[4];
        #pragma unroll
        for (int j = 0; j < 4; ++j)
            v[j] = *(const uint4*)(embh + (long)cur[j] * EMB_DIM + d * 8);

        if (it + 1 < nR) {
            const int base = (it + 1) << 4;
            #pragma unroll
            for (int j = 0; j < 4; ++j) nxt[j] = sidx[w][base + g + 4 * j];
        }

        #pragma unroll
        for (int j = 0; j < 4; ++j) {
            const unsigned c0 = v[j].x, c1 = v[j].y, c2 = v[j].z, c3 = v[j].w;
            acc[j][0] += __uint_as_float(c0 << 16);
            acc[j][1] += __uint_as_float(c0 & 0xffff0000u);
            acc[j][2] += __uint_as_float(c1 << 16);
            acc[j][3] += __uint_as_float(c1 & 0xffff0000u);
            acc[j][4] += __uint_as_float(c2 << 16);
            acc[j][5] += __uint_as_float(c2 & 0xffff0000u);
            acc[j][6] += __uint_as_float(c3 << 16);
            acc[j][7] += __uint_as_float(c3 & 0xffff0000u);
        }
        #pragma unroll
        for (int j = 0; j < 4; ++j) cur[j] = nxt[j];
    }

    // Reduce the 4 unroll slots, then across the 4 groups via shuffles:
    // lane l (<16) ends with the full sum for slot l (dims 8l..8l+7).
    float v8[8];
    #pragma unroll
    for (int f = 0; f < 8; ++f) {
        float s = acc[0][f] + acc[1][f] + acc[2][f] + acc[3][f];
        s += __shfl_down(s, 32);
        s += __shfl_down(s, 16);
        v8[f] = s;
    }
    if (lane < 16) {
        const float invL = 1.0f / (float)L;
        float4 q0 = make_float4(v8[0] * invL, v8[1] * invL, v8[2] * invL, v8[3] * invL);
        float4 q1 = make_float4(v8[4] * invL, v8[5] * invL, v8[6] * invL, v8[7] * invL);
        *(float4*)&P[w][8 * lane]     = q0;
        *(float4*)&P[w][8 * lane + 4] = q1;
    }
    __syncthreads();

    // Layer 1: hidden unit h = t&255 for 4 rows (r0 = (t>>8)*4).
    {
        const int h  = t & 255;
        const int r0 = (t >> 8) * 4;
        float a0 = 0.f, a1 = 0.f, a2 = 0.f, a3 = 0.f;
        for (int k4 = 0; k4 < EMB_DIM; k4 += 4) {
            const float4 p0 = *(const float4*)&P[r0 + 0][k4];
            const float4 p1 = *(const float4*)&P[r0 + 1][k4];
            const float4 p2 = *(const float4*)&P[r0 + 2][k4];
            const float4 p3 = *(const float4*)&P[r0 + 3][k4];
            #pragma unroll
            for (int kk = 0; kk < 4; ++kk) {
                const float wv = W1[(k4 + kk) * HIDDEN + h];
                const float e0 = (kk == 0) ? p0.x : (kk == 1) ? p0.y : (kk == 2) ? p0.z : p0.w;
                const float e1 = (kk == 0) ? p1.x : (kk == 1) ? p1.y : (kk == 2) ? p1.z : p1.w;
                const float e2 = (kk == 0) ? p2.x : (kk == 1) ? p2.y : (kk == 2) ? p2.z : p2.w;
                const float e3 = (kk == 0) ? p3.x : (kk == 1) ? p3.y : (kk == 2) ? p3.z : p3.w;
                a0 += e0 * wv; a1 += e1 * wv; a2 += e2 * wv; a3 += e3 * wv;
            }
        }
        const float bb = b1[h];
        H[r0 + 0][h] = fmaxf(a0 + bb, 0.f);
        H[r0 + 1][h] = fmaxf(a1 + bb, 0.f);
        H[r0 + 2][h] = fmaxf(a2 + bb, 0.f);
        H[r0 + 3][h] = fmaxf(a3 + bb, 0.f);
    }
    __syncthreads();

    // Layer 2: wave r handles row r; lanes 0..19 = classes. 2-way ILP.
    if (lane < NUM_CLASSES) {
        const int r = w;
        const int c = lane;
        float a0 = 0.f, a1 = 0.f;
        for (int k = 0; k < HIDDEN; k += 2) {
            a0 += H[r][k]     * W2[(k)     * NUM_CLASSES + c];
            a1 += H[r][k + 1] * W2[(k + 1) * NUM_CLASSES + c];
        }
        out[(long)(b0 + r) * NUM_CLASSES + c] = a0 + a1 + b2[c];
    }
}

extern "C" void kernel_launch(void* const* d_in, const int* in_sizes, int n_in,
                              void* d_out, int out_size, void* d_ws, size_t ws_size,
                              hipStream_t stream) {
    const int*   x    = (const int*)d_in[0];
    const int*   lens = (const int*)d_in[1];
    const float* emb  = (const float*)d_in[2];
    const float* W1   = (const float*)d_in[3];
    const float* b1   = (const float*)d_in[4];
    const float* W2   = (const float*)d_in[5];
    const float* b2   = (const float*)d_in[6];
    float*       out  = (float*)d_out;

    unsigned short* embh = (unsigned short*)d_ws;   // 25.6 MB bf16 table

    convert_kernel<<<(VOCAB * EMB_DIM) / (8 * 256), 256, 0, stream>>>(emb, embh);
    fused_kernel<<<B / RB, NT, 0, stream>>>(x, lens, embh, W1, b1, W2, b2, out);
}